// Round 3
// baseline (208.341 us; speedup 1.0000x reference)
//
#include <hip/hip_runtime.h>

// QSoftmax (quantized softmax, 8-bit LUT) — B=8, S=2048.
//
// With exp_zero = 1, normed_zero = 0, multiplier > 0, and
// LUT[k] = round(exp(k)) >= 1, every output element is
//   clip(round((expd-1) * (1/rowsum - 1) * mult), 0, 255)
// where (expd-1) >= 0, (1/rowsum - 1) < 0 strictly, mult > 0
// => round(r) <= 0 => output is identically 0.
//
// Single fused kernel: each block re-verifies those preconditions from the
// actual device-side LUT/scalars (1 KB LUT read, L2-broadcast; resolved via
// __syncthreads_and), then either streams zeros (write-only roofline) or
// runs the faithful full computation as a correctness fallback. One kernel,
// no workspace, no serialized guard launch.

#define QS_S 2048   // row length (last dim)

__global__ __launch_bounds__(256) void qs_fused(
    const int*   __restrict__ inp,
    const float* __restrict__ LUT,
    const float* __restrict__ es_p, const float* __restrict__ ez_p,
    const float* __restrict__ ns_p, const float* __restrict__ nz_p,
    float* __restrict__ out)
{
    const int tid = threadIdx.x;
    const long base = (long)blockIdx.x * QS_S;
    float4* __restrict__ outv = (float4*)(out + base);

    __shared__ float lut_s[256];
    __shared__ float wsum[4];

    // ---- in-block guard (also stages LUT for the fallback) ----
    const float L  = LUT[tid];
    const float es = *es_p, ez = *ez_p, ns = *ns_p, nz = *nz_p;
    const float mult = es * (1.0f / es) / ns;   // same fp32 op order as ref
    lut_s[tid] = L;

    // (a) LUT[k] >= ez          => a_zeroed >= 0 for any gathered element
    // (b) S*LUT[k] > 2*ez       => rowsum > 2*ez => denom < 1/ez strictly
    //                              => b_zeroed < 0 strictly (no inf*0 NaN)
    // (c) ez > 0, mult > 0      => product term <= 0, never NaN
    // (d) nz < 0.5              => round(r) <= 0 => clip(...,0,255) == 0
    // NaN in any input fails a comparison => falls back. All-thread AND:
    int ok = (L >= ez) && ((float)QS_S * L > 2.0f * ez)
           && (ez > 0.0f) && (mult > 0.0f) && (nz < 0.5f);
    ok = __syncthreads_and(ok);   // doubles as the barrier publishing lut_s

    if (ok) {
        // All-zero fold: write-only streaming, fully coalesced (32 B/lane).
        const float4 z = make_float4(0.f, 0.f, 0.f, 0.f);
        outv[tid]       = z;
        outv[tid + 256] = z;
        return;
    }

    // ---------- faithful fallback (reference semantics) ----------
    const int4* __restrict__ iv = (const int4*)(inp + base);
    const int4 a0 = iv[tid];
    const int4 a1 = iv[tid + 256];

    // JAX gather clamps out-of-range indices.
    auto lu = [&](int v) -> float {
        v = v < 0 ? 0 : (v > 255 ? 255 : v);
        return lut_s[v];
    };
    const float e0 = lu(a0.x), e1 = lu(a0.y), e2 = lu(a0.z), e3 = lu(a0.w);
    const float e4 = lu(a1.x), e5 = lu(a1.y), e6 = lu(a1.z), e7 = lu(a1.w);

    // Row sum (fp32): wave butterfly then cross-wave via LDS.
    float s = ((e0 + e1) + (e2 + e3)) + ((e4 + e5) + (e6 + e7));
    #pragma unroll
    for (int off = 32; off > 0; off >>= 1) s += __shfl_down(s, off);
    if ((tid & 63) == 0) wsum[tid >> 6] = s;
    __syncthreads();
    const float total = (wsum[0] + wsum[1]) + (wsum[2] + wsum[3]);

    const float denom = 1.0f / total;
    const float bz    = denom - 1.0f / ez;

    auto qm = [&](float e) -> float {
        const float r = (e - ez) * bz * mult + nz;
        return fminf(fmaxf(rintf(r), 0.0f), 255.0f);  // rintf = half-to-even, as jnp.round
    };
    outv[tid]       = make_float4(qm(e0), qm(e1), qm(e2), qm(e3));
    outv[tid + 256] = make_float4(qm(e4), qm(e5), qm(e6), qm(e7));
}

extern "C" void kernel_launch(void* const* d_in, const int* in_sizes, int n_in,
                              void* d_out, int out_size, void* d_ws, size_t ws_size,
                              hipStream_t stream) {
    const int*   inp = (const int*)  d_in[0];
    const float* LUT = (const float*)d_in[1];
    const float* es  = (const float*)d_in[2];
    const float* ez  = (const float*)d_in[3];
    const float* ns  = (const float*)d_in[4];
    const float* nz  = (const float*)d_in[5];
    float* out = (float*)d_out;

    const int rows = in_sizes[0] / QS_S;   // B*S = 16384

    qs_fused<<<rows, 256, 0, stream>>>(inp, LUT, es, ez, ns, nz, out);
}